// Round 4
// baseline (282.142 us; speedup 1.0000x reference)
//
#include <hip/hip_runtime.h>
#include <stdint.h>

#define T_SEQ 4096
#define CEMB 768
#define HS 64

typedef __attribute__((ext_vector_type(8))) short bf16x8;
typedef __attribute__((ext_vector_type(16))) float f32x16;

__device__ __forceinline__ short bfru(float f) {   // round-half-up to bf16
    uint32_t u = __builtin_bit_cast(uint32_t, f);
    return (short)((u + 0x8000u) >> 16);
}
__device__ __forceinline__ uint32_t pack2(float a, float b) {
    return (uint32_t)(uint16_t)bfru(a) | ((uint32_t)(uint16_t)bfru(b) << 16);
}

// 768^-0.5 * log2(e): fold attention scale AND exp->exp2 conversion into Q
#define QSCALE (0.036084391824351615f * 1.4426950408889634f)

// ---------------- prep: W -> bf16 MFMA B-fragment layout (coalesced) ----------------
__global__ __launch_bounds__(256) void prep_wt(const float* __restrict__ Wq,
                                               const float* __restrict__ Wk,
                                               const float* __restrict__ Wv,
                                               short* __restrict__ wtf) {
    const int p = blockIdx.x;                 // ct*48 + kq
    const int ct = p / 48, kq = p % 48;
    const int tid = threadIdx.x;
    const int lane = tid & 63, jp = tid >> 6;
    const int l31 = lane & 31, lhi = lane >> 5;
    const int k = kq * 16 + lhi * 8 + jp * 2;
    const int nn = ct * 32 + l31;
    const float* W = nn < 64 ? Wq : (nn < 128 ? Wk : Wv);
    const int col = nn & 63;
    uint32_t lo = (uint16_t)bfru(W[k * 64 + col]);
    uint32_t hi = (uint16_t)bfru(W[(k + 1) * 64 + col]);
    *(uint32_t*)&wtf[(p * 64 + lane) * 8 + jp * 2] = lo | (hi << 16);
}

// ---------------- fused QKV projection: no LDS staging, no barriers ----------------
// grid 512 x 256 (4 waves). Wave = rg(2 row-groups of 32) x cb(2 ct-triples).
__global__ __launch_bounds__(256, 2) void qkv_proj(const float* __restrict__ x,
        const float* __restrict__ bq, const float* __restrict__ bk, const float* __restrict__ bv,
        const short* __restrict__ wtf,
        short* __restrict__ qo, short* __restrict__ ko, short* __restrict__ vto) {
    __shared__ short Vtr[2][64 * 40];   // per-rg wave-private V transpose staging

    const int tid  = threadIdx.x;
    const int wave = tid >> 6, lane = tid & 63;
    const int l31  = lane & 31, lhi = lane >> 5;
    const int rg = wave & 1, cb = wave >> 1;
    const int row0 = blockIdx.x * 64 + rg * 32;      // this wave's 32 rows

    f32x16 acc[3];
    #pragma unroll
    for (int c = 0; c < 3; ++c) {
        const int nn = (cb * 3 + c) * 32 + l31;
        const float bb = nn < 64 ? bq[nn] : (nn < 128 ? bk[nn - 64] : bv[nn - 128]);
        #pragma unroll
        for (int r = 0; r < 16; ++r) acc[c][r] = bb;
    }

    const float* xr = x + (long)(row0 + l31) * CEMB;
    for (int kt = 0; kt < 12; ++kt) {
        #pragma unroll
        for (int kc = 0; kc < 4; ++kc) {
            const float* px = xr + kt * 64 + kc * 16 + lhi * 8;
            float4 a = *(const float4*)px, b2 = *(const float4*)(px + 4);
            bf16x8 af;
            af[0]=bfru(a.x);  af[1]=bfru(a.y);  af[2]=bfru(a.z);  af[3]=bfru(a.w);
            af[4]=bfru(b2.x); af[5]=bfru(b2.y); af[6]=bfru(b2.z); af[7]=bfru(b2.w);
            #pragma unroll
            for (int c = 0; c < 3; ++c) {
                bf16x8 wf = *(const bf16x8*)&wtf[((cb * 3 + c) * 48 + kt * 4 + kc) * 512 + lane * 8];
                acc[c] = __builtin_amdgcn_mfma_f32_32x32x16_bf16(af, wf, acc[c], 0, 0, 0);
            }
        }
    }

    // epilogue. C/D: col = l31, row = (r&3)+8*(r>>2)+4*lhi
    #pragma unroll
    for (int c = 0; c < 3; ++c) {
        const int ct = cb * 3 + c;
        if (ct < 2) {
            #pragma unroll
            for (int r = 0; r < 16; ++r) {
                const int row = (r & 3) + 8 * (r >> 2) + 4 * lhi;
                qo[(long)(row0 + row) * HS + ct * 32 + l31] = bfru(acc[c][r] * QSCALE);
            }
        } else if (ct < 4) {
            #pragma unroll
            for (int r = 0; r < 16; ++r) {
                const int row = (r & 3) + 8 * (r >> 2) + 4 * lhi;
                ko[(long)(row0 + row) * HS + (ct - 2) * 32 + l31] = bfru(acc[c][r]);
            }
        } else {    // v: wave-private transpose, packed b64 writes
            const int vcol = (ct - 4) * 32 + l31;
            #pragma unroll
            for (int quad = 0; quad < 4; ++quad) {
                uint32_t lo = pack2(acc[c][quad * 4 + 0], acc[c][quad * 4 + 1]);
                uint32_t hi = pack2(acc[c][quad * 4 + 2], acc[c][quad * 4 + 3]);
                uint32_t* dst = (uint32_t*)&Vtr[rg][vcol * 40 + quad * 8 + lhi * 4];
                dst[0] = lo; dst[1] = hi;
            }
        }
    }
    if (cb == 1) {   // write v transposed: vto[b][h][t], 32 t-values per lane
        const int b = row0 >> 12, t0 = row0 & 4095;
        short* dst = vto + ((long)b * HS + lane) * T_SEQ + t0;
        #pragma unroll
        for (int i = 0; i < 4; ++i)
            *(bf16x8*)(dst + i * 8) = *(const bf16x8*)&Vtr[rg][lane * 40 + i * 8];
    }
}

// ---------------- fused attention: S^T form, no barriers, K/V direct from L2 ----------------
// grid = 8b * ks * 16qt blocks x 256 threads. Wave = 64 qrows; BQ=256/block; BKt=64.
// l is summed from the bf16-ROUNDED P values (exactly consistent with the PV operand),
// so P rounding cancels in O/l — the r3 failure (3.4e-3) traced to inconsistent l.
__global__ __launch_bounds__(256, 2) void attn(const short* __restrict__ qm,
        const short* __restrict__ km, const short* __restrict__ vtm,
        float* __restrict__ Op, float* __restrict__ lp, const int ks,
        float* __restrict__ outdirect) {
    __shared__ short P[4][2][32 * 72];   // wave-private P^T [qrow][key], pitch 72 (36.9 KB)

    const int tid  = threadIdx.x;
    const int wave = tid >> 6, lane = tid & 63;
    const int l31  = lane & 31, lhi = lane >> 5;
    const int idx  = blockIdx.x;
    const int b = idx & 7, s = (idx >> 3) % ks, qt = idx / (8 * ks);
    const int slab = T_SEQ / ks, nkt = slab / 64;
    const int qrow0 = qt * 256 + wave * 64;

    const short* qb = qm + ((long)b * T_SEQ + qrow0) * HS;
    const short* kb = km + ((long)b * T_SEQ + s * slab) * HS;
    const short* vb = vtm + (long)b * HS * T_SEQ + s * slab;

    bf16x8 qf[2][4];                       // B-frags: [n=qrow][k=h]
    #pragma unroll
    for (int q = 0; q < 2; ++q)
        #pragma unroll
        for (int kc = 0; kc < 4; ++kc)
            qf[q][kc] = *(const bf16x8*)&qb[(q * 32 + l31) * HS + kc * 16 + lhi * 8];

    f32x16 oacc[2][2] = {};                // [ht][qsub], O^T[h][qrow]
    float lsum[2] = {0.f, 0.f};
    short* pw[2] = { &P[wave][0][0], &P[wave][1][0] };

    for (int kt = 0; kt < nkt; ++kt) {
        const int k0 = kt * 64;
        bf16x8 kf[2][4];                   // A-frags: [m=key][k=h]
        #pragma unroll
        for (int m = 0; m < 2; ++m)
            #pragma unroll
            for (int kc = 0; kc < 4; ++kc)
                kf[m][kc] = *(const bf16x8*)&kb[(k0 + m * 32 + l31) * HS + kc * 16 + lhi * 8];
        bf16x8 vf[2][4];                   // A-frags: [m=h][k=key]
        #pragma unroll
        for (int ht = 0; ht < 2; ++ht)
            #pragma unroll
            for (int kc2 = 0; kc2 < 4; ++kc2)
                vf[ht][kc2] = *(const bf16x8*)&vb[(ht * 32 + l31) * T_SEQ + k0 + kc2 * 16 + lhi * 8];

        // S^T = K Q^T; C/D: col=qrow=l31, row=key=(r&3)+8(r>>2)+4lhi+32m
        #pragma unroll
        for (int m = 0; m < 2; ++m) {
            #pragma unroll
            for (int q = 0; q < 2; ++q) {
                f32x16 z = {};
                #pragma unroll
                for (int kc = 0; kc < 4; ++kc)
                    z = __builtin_amdgcn_mfma_f32_32x32x16_bf16(kf[m][kc], qf[q][kc], z, 0, 0, 0);
                #pragma unroll
                for (int quad = 0; quad < 4; ++quad) {
                    // round exp to bf16 FIRST; sum the rounded values (consistency with PV)
                    uint32_t u0 = (__builtin_bit_cast(uint32_t, __builtin_amdgcn_exp2f(z[quad * 4 + 0])) + 0x8000u) & 0xFFFF0000u;
                    uint32_t u1 = (__builtin_bit_cast(uint32_t, __builtin_amdgcn_exp2f(z[quad * 4 + 1])) + 0x8000u) & 0xFFFF0000u;
                    uint32_t u2 = (__builtin_bit_cast(uint32_t, __builtin_amdgcn_exp2f(z[quad * 4 + 2])) + 0x8000u) & 0xFFFF0000u;
                    uint32_t u3 = (__builtin_bit_cast(uint32_t, __builtin_amdgcn_exp2f(z[quad * 4 + 3])) + 0x8000u) & 0xFFFF0000u;
                    lsum[q] += (__builtin_bit_cast(float, u0) + __builtin_bit_cast(float, u1))
                             + (__builtin_bit_cast(float, u2) + __builtin_bit_cast(float, u3));
                    uint32_t* dst = (uint32_t*)&pw[q][l31 * 72 + m * 32 + quad * 8 + lhi * 4];
                    dst[0] = (u0 >> 16) | u1;        // shorts: [e0][e1]
                    dst[1] = (u2 >> 16) | u3;        // shorts: [e2][e3]
                }
            }
        }
        // O^T += V^T P^T : A=vf[m=h][k=key], B=pf[k=key][n=qrow]
        #pragma unroll
        for (int kc2 = 0; kc2 < 4; ++kc2) {
            bf16x8 pf0 = *(const bf16x8*)&pw[0][l31 * 72 + kc2 * 16 + lhi * 8];
            bf16x8 pf1 = *(const bf16x8*)&pw[1][l31 * 72 + kc2 * 16 + lhi * 8];
            #pragma unroll
            for (int ht = 0; ht < 2; ++ht) {
                oacc[ht][0] = __builtin_amdgcn_mfma_f32_32x32x16_bf16(vf[ht][kc2], pf0, oacc[ht][0], 0, 0, 0);
                oacc[ht][1] = __builtin_amdgcn_mfma_f32_32x32x16_bf16(vf[ht][kc2], pf1, oacc[ht][1], 0, 0, 0);
            }
        }
    }

    lsum[0] += __shfl_xor(lsum[0], 32, 64);    // lhi halves hold complementary keys
    lsum[1] += __shfl_xor(lsum[1], 32, 64);

    const long rowg = (long)b * T_SEQ + qrow0;
    if (outdirect) {
        float* ob = outdirect + rowg * HS;
        #pragma unroll
        for (int q = 0; q < 2; ++q) {
            const float inv = 1.0f / lsum[q];
            #pragma unroll
            for (int ht = 0; ht < 2; ++ht)
                #pragma unroll
                for (int r = 0; r < 16; ++r) {
                    const int h = (r & 3) + 8 * (r >> 2) + 4 * lhi + 32 * ht;
                    ob[(long)(q * 32 + l31) * HS + h] = oacc[ht][q][r] * inv;
                }
        }
    } else {
        float* op = Op + ((long)s * 32768 + rowg) * HS;
        #pragma unroll
        for (int q = 0; q < 2; ++q) {
            #pragma unroll
            for (int ht = 0; ht < 2; ++ht)
                #pragma unroll
                for (int r = 0; r < 16; ++r) {
                    const int h = (r & 3) + 8 * (r >> 2) + 4 * lhi + 32 * ht;
                    op[(long)(q * 32 + l31) * HS + h] = oacc[ht][q][r];
                }
            if (lhi == 0)
                lp[(long)s * 32768 + rowg + q * 32 + l31] = lsum[q];
        }
    }
}

// ---------------- combine partials: out = sum_s O_s / sum_s l_s ----------------
__global__ __launch_bounds__(256) void combine(const float4* __restrict__ Op,
        const float* __restrict__ lp, float4* __restrict__ out, const int ks) {
    const int idx = blockIdx.x * 256 + threadIdx.x;   // 524288 = 32768 rows x 16 float4
    const int row = idx >> 4, h4 = idx & 15;
    float ox = 0.f, oy = 0.f, oz = 0.f, ow = 0.f, l = 0.f;
    for (int s = 0; s < ks; ++s) {
        float4 t = Op[(long)(s * 32768 + row) * 16 + h4];
        ox += t.x; oy += t.y; oz += t.z; ow += t.w;
        l += lp[s * 32768 + row];
    }
    const float inv = 1.0f / l;
    float4 o; o.x = ox * inv; o.y = oy * inv; o.z = oz * inv; o.w = ow * inv;
    out[(long)row * 16 + h4] = o;
}

extern "C" void kernel_launch(void* const* d_in, const int* in_sizes, int n_in,
                              void* d_out, int out_size, void* d_ws, size_t ws_size,
                              hipStream_t stream) {
    const float* x  = (const float*)d_in[0];
    const float* Wq = (const float*)d_in[1];
    const float* bq = (const float*)d_in[2];
    const float* Wk = (const float*)d_in[3];
    const float* bk = (const float*)d_in[4];
    const float* Wv = (const float*)d_in[5];
    const float* bv = (const float*)d_in[6];

    char* ws = (char*)d_ws;
    short* qo  = (short*)(ws);                     // 4 MB
    short* ko  = (short*)(ws + (4u << 20));        // 4 MB
    short* vto = (short*)(ws + (8u << 20));        // 4 MB  [b][h][t]
    short* wtf = (short*)(ws + (12u << 20));       // 288 KB
    const size_t opOff = 12582912u + 294912u;
    float* Op = (float*)(ws + opOff);

    const size_t per_s = 8388608u + 131072u;
    int ks = (ws_size >= opOff + 4 * per_s) ? 4
           : (ws_size >= opOff + 2 * per_s) ? 2 : 1;
    float* lp = (float*)(ws + opOff + (size_t)ks * 8388608u);

    prep_wt<<<288, 256, 0, stream>>>(Wq, Wk, Wv, wtf);
    qkv_proj<<<512, 256, 0, stream>>>(x, bq, bk, bv, wtf, qo, ko, vto);
    attn<<<8 * ks * 16, 256, 0, stream>>>(qo, ko, vto, Op, lp, ks,
                                          ks == 1 ? (float*)d_out : nullptr);
    if (ks > 1)
        combine<<<2048, 256, 0, stream>>>((const float4*)Op, lp, (float4*)d_out, ks);
}

// Round 5
// 247.243 us; speedup vs baseline: 1.1412x; 1.1412x over previous
//
#include <hip/hip_runtime.h>
#include <stdint.h>

#define T_SEQ 4096
#define CEMB 768
#define HS 64

typedef __attribute__((ext_vector_type(8))) short bf16x8;
typedef __attribute__((ext_vector_type(16))) float f32x16;

__device__ __forceinline__ short bfru(float f) {   // round-half-up to bf16
    uint32_t u = __builtin_bit_cast(uint32_t, f);
    return (short)((u + 0x8000u) >> 16);
}
__device__ __forceinline__ uint32_t pack2(float a, float b) {
    return (uint32_t)(uint16_t)bfru(a) | ((uint32_t)(uint16_t)bfru(b) << 16);
}

// 768^-0.5 * log2(e): fold attention scale AND exp->exp2 conversion into Q
#define QSCALE (0.036084391824351615f * 1.4426950408889634f)

// ---------------- prep: W -> bf16 MFMA B-fragment layout (coalesced) ----------------
__global__ __launch_bounds__(256) void prep_wt(const float* __restrict__ Wq,
                                               const float* __restrict__ Wk,
                                               const float* __restrict__ Wv,
                                               short* __restrict__ wtf) {
    const int p = blockIdx.x;                 // ct*48 + kq
    const int ct = p / 48, kq = p % 48;
    const int tid = threadIdx.x;
    const int lane = tid & 63, jp = tid >> 6;
    const int l31 = lane & 31, lhi = lane >> 5;
    const int k = kq * 16 + lhi * 8 + jp * 2;
    const int nn = ct * 32 + l31;
    const float* W = nn < 64 ? Wq : (nn < 128 ? Wk : Wv);
    const int col = nn & 63;
    uint32_t lo = (uint16_t)bfru(W[k * 64 + col]);
    uint32_t hi = (uint16_t)bfru(W[(k + 1) * 64 + col]);
    *(uint32_t*)&wtf[(p * 64 + lane) * 8 + jp * 2] = lo | (hi << 16);
}

// ---------------- fused QKV projection: coalesced LDS staging + reg prefetch ----------------
// grid 512 x 256 (4 waves). BM=64. Wave = rg(row-group of 32) x cb(ct-triple).
__global__ __launch_bounds__(256, 2) void qkv_proj(const float* __restrict__ x,
        const float* __restrict__ bq, const float* __restrict__ bk, const float* __restrict__ bv,
        const short* __restrict__ wtf,
        short* __restrict__ qo, short* __restrict__ ko, short* __restrict__ vto) {
    __shared__ short S[64 * 72];        // A tile [row][k] pitch 72 (9.2 KB)
    __shared__ short Vtr[2][64 * 40];   // per-rg wave-private V transpose staging (10 KB)

    const int tid  = threadIdx.x;
    const int wave = tid >> 6, lane = tid & 63;
    const int l31  = lane & 31, lhi = lane >> 5;
    const int rg = wave & 1, cb = wave >> 1;
    const int rowbase = blockIdx.x * 64;

    f32x16 acc[3];                      // bias folded into accumulator init
    #pragma unroll
    for (int c = 0; c < 3; ++c) {
        const int nn = (cb * 3 + c) * 32 + l31;
        const float bb = nn < 64 ? bq[nn] : (nn < 128 ? bk[nn - 64] : bv[nn - 128]);
        #pragma unroll
        for (int r = 0; r < 16; ++r) acc[c][r] = bb;
    }

    // staging map: instr i covers rows i*16 + (tid>>4), 16 lanes sweep 256B contiguous
    const int g = tid >> 4, j16 = tid & 15;
    float4 t[4];
    #pragma unroll
    for (int i = 0; i < 4; ++i)        // prefetch kt=0
        t[i] = *(const float4*)(x + (long)(rowbase + i * 16 + g) * CEMB + j16 * 4);

    for (int kt = 0; kt < 12; ++kt) {
        __syncthreads();               // previous iteration's reads complete
        #pragma unroll
        for (int i = 0; i < 4; ++i) {
            uint32_t* dst = (uint32_t*)&S[(i * 16 + g) * 72 + j16 * 4];
            dst[0] = pack2(t[i].x, t[i].y);
            dst[1] = pack2(t[i].z, t[i].w);
        }
        __syncthreads();
        if (kt < 11) {                 // prefetch next tile while MFMAs run
            #pragma unroll
            for (int i = 0; i < 4; ++i)
                t[i] = *(const float4*)(x + (long)(rowbase + i * 16 + g) * CEMB + (kt + 1) * 64 + j16 * 4);
        }
        #pragma unroll
        for (int kc = 0; kc < 4; ++kc) {
            bf16x8 af = *(const bf16x8*)&S[(rg * 32 + l31) * 72 + kc * 16 + lhi * 8];
            #pragma unroll
            for (int c = 0; c < 3; ++c) {
                bf16x8 wf = *(const bf16x8*)&wtf[((cb * 3 + c) * 48 + kt * 4 + kc) * 512 + lane * 8];
                acc[c] = __builtin_amdgcn_mfma_f32_32x32x16_bf16(af, wf, acc[c], 0, 0, 0);
            }
        }
    }

    const int row0 = rowbase + rg * 32;
    // epilogue. C/D: col = l31, row = (r&3)+8*(r>>2)+4*lhi
    #pragma unroll
    for (int c = 0; c < 3; ++c) {
        const int ct = cb * 3 + c;
        if (ct < 2) {
            #pragma unroll
            for (int r = 0; r < 16; ++r) {
                const int row = (r & 3) + 8 * (r >> 2) + 4 * lhi;
                qo[(long)(row0 + row) * HS + ct * 32 + l31] = bfru(acc[c][r] * QSCALE);
            }
        } else if (ct < 4) {
            #pragma unroll
            for (int r = 0; r < 16; ++r) {
                const int row = (r & 3) + 8 * (r >> 2) + 4 * lhi;
                ko[(long)(row0 + row) * HS + (ct - 2) * 32 + l31] = bfru(acc[c][r]);
            }
        } else {    // v: wave-private transpose, packed b64 writes
            const int vcol = (ct - 4) * 32 + l31;
            #pragma unroll
            for (int quad = 0; quad < 4; ++quad) {
                uint32_t lo = pack2(acc[c][quad * 4 + 0], acc[c][quad * 4 + 1]);
                uint32_t hi = pack2(acc[c][quad * 4 + 2], acc[c][quad * 4 + 3]);
                uint32_t* dst = (uint32_t*)&Vtr[rg][vcol * 40 + quad * 8 + lhi * 4];
                dst[0] = lo; dst[1] = hi;
            }
        }
    }
    if (cb == 1) {   // write v transposed: vto[b][h][t], 32 t-values per lane
        const int b = row0 >> 12, t0 = row0 & 4095;
        short* dst = vto + ((long)b * HS + lane) * T_SEQ + t0;
        #pragma unroll
        for (int i = 0; i < 4; ++i)
            *(bf16x8*)(dst + i * 8) = *(const bf16x8*)&Vtr[rg][lane * 40 + i * 8];
    }
}

// ---------------- fused attention: S^T form, ZERO LDS, P transform via shfl_xor ----------------
// grid = 8b * ks * 16qt blocks x 256 threads. Wave = 64 qrows; BQ=256/block; BKt=64.
// l is summed from the bf16-ROUNDED P values (consistent with PV operand -> rounding cancels).
__global__ __launch_bounds__(256, 2) void attn(const short* __restrict__ qm,
        const short* __restrict__ km, const short* __restrict__ vtm,
        float* __restrict__ Op, float* __restrict__ lp, const int ks,
        float* __restrict__ outdirect) {
    const int tid  = threadIdx.x;
    const int wave = tid >> 6, lane = tid & 63;
    const int l31  = lane & 31, lhi = lane >> 5;
    const int idx  = blockIdx.x;
    const int b = idx & 7, s = (idx >> 3) % ks, qt = idx / (8 * ks);
    const int slab = T_SEQ / ks, nkt = slab / 64;
    const int qrow0 = qt * 256 + wave * 64;

    const short* qb = qm + ((long)b * T_SEQ + qrow0) * HS;
    const short* kb = km + ((long)b * T_SEQ + s * slab) * HS;
    const short* vb = vtm + (long)b * HS * T_SEQ + s * slab;

    bf16x8 qf[2][4];                       // B-frags: [n=qrow][k=h]
    #pragma unroll
    for (int q = 0; q < 2; ++q)
        #pragma unroll
        for (int kc = 0; kc < 4; ++kc)
            qf[q][kc] = *(const bf16x8*)&qb[(q * 32 + l31) * HS + kc * 16 + lhi * 8];

    f32x16 oacc[2][2] = {};                // [ht][qsub], O^T[h][qrow]
    float lsum[2] = {0.f, 0.f};

    for (int kt = 0; kt < nkt; ++kt) {
        const int k0 = kt * 64;
        bf16x8 kf[2][4];                   // A-frags: [m=key][k=h]
        #pragma unroll
        for (int m = 0; m < 2; ++m)
            #pragma unroll
            for (int kc = 0; kc < 4; ++kc)
                kf[m][kc] = *(const bf16x8*)&kb[(k0 + m * 32 + l31) * HS + kc * 16 + lhi * 8];
        bf16x8 vf[2][4];                   // A-frags: [m=h][k=key]
        #pragma unroll
        for (int ht = 0; ht < 2; ++ht)
            #pragma unroll
            for (int kv = 0; kv < 4; ++kv)
                vf[ht][kv] = *(const bf16x8*)&vb[(ht * 32 + l31) * T_SEQ + k0 + kv * 16 + lhi * 8];

        #pragma unroll
        for (int m = 0; m < 2; ++m) {
            #pragma unroll
            for (int q = 0; q < 2; ++q) {
                // S^T = K Q^T; C/D: col=qrow=l31, key = 8*quad + 4*lhi + t (+32m)
                f32x16 z = {};
                #pragma unroll
                for (int kc = 0; kc < 4; ++kc)
                    z = __builtin_amdgcn_mfma_f32_32x32x16_bf16(kf[m][kc], qf[q][kc], z, 0, 0, 0);

                // exp2 -> bf16 (rounded); pack per-quad pairs
                uint32_t w[8];
                #pragma unroll
                for (int qd = 0; qd < 4; ++qd) {
                    uint32_t u0 = (__builtin_bit_cast(uint32_t, __builtin_amdgcn_exp2f(z[qd * 4 + 0])) + 0x8000u) & 0xFFFF0000u;
                    uint32_t u1 = (__builtin_bit_cast(uint32_t, __builtin_amdgcn_exp2f(z[qd * 4 + 1])) + 0x8000u) & 0xFFFF0000u;
                    uint32_t u2 = (__builtin_bit_cast(uint32_t, __builtin_amdgcn_exp2f(z[qd * 4 + 2])) + 0x8000u) & 0xFFFF0000u;
                    uint32_t u3 = (__builtin_bit_cast(uint32_t, __builtin_amdgcn_exp2f(z[qd * 4 + 3])) + 0x8000u) & 0xFFFF0000u;
                    lsum[q] += (__builtin_bit_cast(float, u0) + __builtin_bit_cast(float, u1))
                             + (__builtin_bit_cast(float, u2) + __builtin_bit_cast(float, u3));
                    w[qd * 2 + 0] = (u0 >> 16) | u1;   // shorts [key+0, key+1]
                    w[qd * 2 + 1] = (u2 >> 16) | u3;   // shorts [key+2, key+3]
                }
                // lane-pair exchange (lhi 0<->1): lhi=0 sends quads {1,3}, needs partner {0,2}
                const bool hi = (lhi != 0);
                uint32_t sa0 = hi ? w[0] : w[2], sa1 = hi ? w[1] : w[3];
                uint32_t sb0 = hi ? w[4] : w[6], sb1 = hi ? w[5] : w[7];
                uint32_t ra0 = (uint32_t)__shfl_xor((int)sa0, 32, 64);
                uint32_t ra1 = (uint32_t)__shfl_xor((int)sa1, 32, 64);
                uint32_t rb0 = (uint32_t)__shfl_xor((int)sb0, 32, 64);
                uint32_t rb1 = (uint32_t)__shfl_xor((int)sb1, 32, 64);
                // assemble B-frags: pf[kc2] = keys 16*kc2 + 8*lhi + {0..7} (qrow = l31)
                uint32_t pf0[4], pf1[4];
                pf0[0] = hi ? ra0 : w[0];  pf0[1] = hi ? ra1 : w[1];
                pf0[2] = hi ? w[2] : ra0;  pf0[3] = hi ? w[3] : ra1;
                pf1[0] = hi ? rb0 : w[4];  pf1[1] = hi ? rb1 : w[5];
                pf1[2] = hi ? w[6] : rb0;  pf1[3] = hi ? w[7] : rb1;
                bf16x8 p0 = *(const bf16x8*)pf0, p1 = *(const bf16x8*)pf1;

                // O^T += V^T P^T over this 32-key block
                #pragma unroll
                for (int ht = 0; ht < 2; ++ht) {
                    oacc[ht][q] = __builtin_amdgcn_mfma_f32_32x32x16_bf16(vf[ht][m * 2 + 0], p0, oacc[ht][q], 0, 0, 0);
                    oacc[ht][q] = __builtin_amdgcn_mfma_f32_32x32x16_bf16(vf[ht][m * 2 + 1], p1, oacc[ht][q], 0, 0, 0);
                }
            }
        }
    }

    lsum[0] += __shfl_xor(lsum[0], 32, 64);    // lhi halves hold complementary keys
    lsum[1] += __shfl_xor(lsum[1], 32, 64);

    const long rowg = (long)b * T_SEQ + qrow0;
    if (outdirect) {
        float* ob = outdirect + rowg * HS;
        #pragma unroll
        for (int q = 0; q < 2; ++q) {
            const float inv = 1.0f / lsum[q];
            #pragma unroll
            for (int ht = 0; ht < 2; ++ht)
                #pragma unroll
                for (int r = 0; r < 16; ++r) {
                    const int h = (r & 3) + 8 * (r >> 2) + 4 * lhi + 32 * ht;
                    ob[(long)(q * 32 + l31) * HS + h] = oacc[ht][q][r] * inv;
                }
        }
    } else {
        float* op = Op + ((long)s * 32768 + rowg) * HS;
        #pragma unroll
        for (int q = 0; q < 2; ++q) {
            #pragma unroll
            for (int ht = 0; ht < 2; ++ht)
                #pragma unroll
                for (int r = 0; r < 16; ++r) {
                    const int h = (r & 3) + 8 * (r >> 2) + 4 * lhi + 32 * ht;
                    op[(long)(q * 32 + l31) * HS + h] = oacc[ht][q][r];
                }
            if (lhi == 0)
                lp[(long)s * 32768 + rowg + q * 32 + l31] = lsum[q];
        }
    }
}

// ---------------- combine partials: out = sum_s O_s / sum_s l_s ----------------
__global__ __launch_bounds__(256) void combine(const float4* __restrict__ Op,
        const float* __restrict__ lp, float4* __restrict__ out, const int ks) {
    const int idx = blockIdx.x * 256 + threadIdx.x;   // 524288 = 32768 rows x 16 float4
    const int row = idx >> 4, h4 = idx & 15;
    float ox = 0.f, oy = 0.f, oz = 0.f, ow = 0.f, l = 0.f;
    for (int s = 0; s < ks; ++s) {
        float4 t = Op[(long)(s * 32768 + row) * 16 + h4];
        ox += t.x; oy += t.y; oz += t.z; ow += t.w;
        l += lp[s * 32768 + row];
    }
    const float inv = 1.0f / l;
    float4 o; o.x = ox * inv; o.y = oy * inv; o.z = oz * inv; o.w = ow * inv;
    out[(long)row * 16 + h4] = o;
}

extern "C" void kernel_launch(void* const* d_in, const int* in_sizes, int n_in,
                              void* d_out, int out_size, void* d_ws, size_t ws_size,
                              hipStream_t stream) {
    const float* x  = (const float*)d_in[0];
    const float* Wq = (const float*)d_in[1];
    const float* bq = (const float*)d_in[2];
    const float* Wk = (const float*)d_in[3];
    const float* bk = (const float*)d_in[4];
    const float* Wv = (const float*)d_in[5];
    const float* bv = (const float*)d_in[6];

    char* ws = (char*)d_ws;
    short* qo  = (short*)(ws);                     // 4 MB
    short* ko  = (short*)(ws + (4u << 20));        // 4 MB
    short* vto = (short*)(ws + (8u << 20));        // 4 MB  [b][h][t]
    short* wtf = (short*)(ws + (12u << 20));       // 288 KB
    const size_t opOff = 12582912u + 294912u;
    float* Op = (float*)(ws + opOff);

    const size_t per_s = 8388608u + 131072u;
    int ks = (ws_size >= opOff + 4 * per_s) ? 4
           : (ws_size >= opOff + 2 * per_s) ? 2 : 1;
    float* lp = (float*)(ws + opOff + (size_t)ks * 8388608u);

    prep_wt<<<288, 256, 0, stream>>>(Wq, Wk, Wv, wtf);
    qkv_proj<<<512, 256, 0, stream>>>(x, bq, bk, bv, wtf, qo, ko, vto);
    attn<<<8 * ks * 16, 256, 0, stream>>>(qo, ko, vto, Op, lp, ks,
                                          ks == 1 ? (float*)d_out : nullptr);
    if (ks > 1)
        combine<<<2048, 256, 0, stream>>>((const float4*)Op, lp, (float4*)d_out, ks);
}

// Round 6
// 232.223 us; speedup vs baseline: 1.2150x; 1.0647x over previous
//
#include <hip/hip_runtime.h>
#include <stdint.h>

#define T_SEQ 4096
#define CEMB 768
#define HS 64

typedef __attribute__((ext_vector_type(8))) short bf16x8;
typedef __attribute__((ext_vector_type(16))) float f32x16;

__device__ __forceinline__ short bfru(float f) {   // round-half-up to bf16
    uint32_t u = __builtin_bit_cast(uint32_t, f);
    return (short)((u + 0x8000u) >> 16);
}
__device__ __forceinline__ uint32_t pack2(float a, float b) {
    return (uint32_t)(uint16_t)bfru(a) | ((uint32_t)(uint16_t)bfru(b) << 16);
}

// 768^-0.5 * log2(e): fold attention scale AND exp->exp2 conversion into Q
#define QSCALE (0.036084391824351615f * 1.4426950408889634f)

// ---------------- prep: W -> bf16 MFMA B-fragment layout (coalesced) ----------------
__global__ __launch_bounds__(256) void prep_wt(const float* __restrict__ Wq,
                                               const float* __restrict__ Wk,
                                               const float* __restrict__ Wv,
                                               short* __restrict__ wtf) {
    const int p = blockIdx.x;                 // ct*48 + kq
    const int ct = p / 48, kq = p % 48;
    const int tid = threadIdx.x;
    const int lane = tid & 63, jp = tid >> 6;
    const int l31 = lane & 31, lhi = lane >> 5;
    const int k = kq * 16 + lhi * 8 + jp * 2;
    const int nn = ct * 32 + l31;
    const float* W = nn < 64 ? Wq : (nn < 128 ? Wk : Wv);
    const int col = nn & 63;
    uint32_t lo = (uint16_t)bfru(W[k * 64 + col]);
    uint32_t hi = (uint16_t)bfru(W[(k + 1) * 64 + col]);
    *(uint32_t*)&wtf[(p * 64 + lane) * 8 + jp * 2] = lo | (hi << 16);
}

// ---------------- fused QKV projection: coalesced LDS staging + reg prefetch ----------------
// grid 512 x 256 (4 waves). BM=64. Wave = rg(row-group of 32) x cb(ct-triple).
__global__ __launch_bounds__(256, 2) void qkv_proj(const float* __restrict__ x,
        const float* __restrict__ bq, const float* __restrict__ bk, const float* __restrict__ bv,
        const short* __restrict__ wtf,
        short* __restrict__ qo, short* __restrict__ ko, short* __restrict__ vto) {
    __shared__ short S[64 * 72];        // A tile [row][k] pitch 72 (9.2 KB)
    __shared__ short Vtr[2][64 * 40];   // per-rg wave-private V transpose staging (10 KB)

    const int tid  = threadIdx.x;
    const int wave = tid >> 6, lane = tid & 63;
    const int l31  = lane & 31, lhi = lane >> 5;
    const int rg = wave & 1, cb = wave >> 1;
    const int rowbase = blockIdx.x * 64;

    f32x16 acc[3];                      // bias folded into accumulator init
    #pragma unroll
    for (int c = 0; c < 3; ++c) {
        const int nn = (cb * 3 + c) * 32 + l31;
        const float bb = nn < 64 ? bq[nn] : (nn < 128 ? bk[nn - 64] : bv[nn - 128]);
        #pragma unroll
        for (int r = 0; r < 16; ++r) acc[c][r] = bb;
    }

    // staging map: instr i covers rows i*16 + (tid>>4), 16 lanes sweep 256B contiguous
    const int g = tid >> 4, j16 = tid & 15;
    float4 t[4];
    #pragma unroll
    for (int i = 0; i < 4; ++i)        // prefetch kt=0
        t[i] = *(const float4*)(x + (long)(rowbase + i * 16 + g) * CEMB + j16 * 4);

    for (int kt = 0; kt < 12; ++kt) {
        __syncthreads();               // previous iteration's reads complete
        #pragma unroll
        for (int i = 0; i < 4; ++i) {
            uint32_t* dst = (uint32_t*)&S[(i * 16 + g) * 72 + j16 * 4];
            dst[0] = pack2(t[i].x, t[i].y);
            dst[1] = pack2(t[i].z, t[i].w);
        }
        __syncthreads();
        if (kt < 11) {                 // prefetch next tile while MFMAs run
            #pragma unroll
            for (int i = 0; i < 4; ++i)
                t[i] = *(const float4*)(x + (long)(rowbase + i * 16 + g) * CEMB + (kt + 1) * 64 + j16 * 4);
        }
        #pragma unroll
        for (int kc = 0; kc < 4; ++kc) {
            bf16x8 af = *(const bf16x8*)&S[(rg * 32 + l31) * 72 + kc * 16 + lhi * 8];
            #pragma unroll
            for (int c = 0; c < 3; ++c) {
                bf16x8 wf = *(const bf16x8*)&wtf[((cb * 3 + c) * 48 + kt * 4 + kc) * 512 + lane * 8];
                acc[c] = __builtin_amdgcn_mfma_f32_32x32x16_bf16(af, wf, acc[c], 0, 0, 0);
            }
        }
    }

    const int row0 = rowbase + rg * 32;
    // epilogue. C/D: col = l31, row = (r&3)+8*(r>>2)+4*lhi
    #pragma unroll
    for (int c = 0; c < 3; ++c) {
        const int ct = cb * 3 + c;
        if (ct < 2) {
            #pragma unroll
            for (int r = 0; r < 16; ++r) {
                const int row = (r & 3) + 8 * (r >> 2) + 4 * lhi;
                qo[(long)(row0 + row) * HS + ct * 32 + l31] = bfru(acc[c][r] * QSCALE);
            }
        } else if (ct < 4) {
            #pragma unroll
            for (int r = 0; r < 16; ++r) {
                const int row = (r & 3) + 8 * (r >> 2) + 4 * lhi;
                ko[(long)(row0 + row) * HS + (ct - 2) * 32 + l31] = bfru(acc[c][r]);
            }
        } else {    // v: wave-private transpose, packed b64 writes
            const int vcol = (ct - 4) * 32 + l31;
            #pragma unroll
            for (int quad = 0; quad < 4; ++quad) {
                uint32_t lo = pack2(acc[c][quad * 4 + 0], acc[c][quad * 4 + 1]);
                uint32_t hi = pack2(acc[c][quad * 4 + 2], acc[c][quad * 4 + 3]);
                uint32_t* dst = (uint32_t*)&Vtr[rg][vcol * 40 + quad * 8 + lhi * 4];
                dst[0] = lo; dst[1] = hi;
            }
        }
    }
    if (cb == 1) {   // write v transposed: vto[b][h][t], 32 t-values per lane
        const int b = row0 >> 12, t0 = row0 & 4095;
        short* dst = vto + ((long)b * HS + lane) * T_SEQ + t0;
        #pragma unroll
        for (int i = 0; i < 4; ++i)
            *(bf16x8*)(dst + i * 8) = *(const bf16x8*)&Vtr[rg][lane * 40 + i * 8];
    }
}

// ---------------- fused attention: LDS-staged K/V (XOR swizzle), shfl-P, key-split ----------------
// grid = 8b * ks * 16qt blocks x 256 threads (4 waves x 64 qrows). BKt=64.
// l summed from the bf16-TRUNCATED P values (consistent with PV operand -> rounding cancels).
__global__ __launch_bounds__(256, 2) void attn(const short* __restrict__ qm,
        const short* __restrict__ km, const short* __restrict__ vtm,
        float* __restrict__ Op, float* __restrict__ lp, const int ks,
        float* __restrict__ outdirect) {
    __shared__ short Kt[64 * 64];   // [key][h], group (h/8) XOR-swizzled by (key&7) — 8 KB
    __shared__ short Vt[64 * 64];   // [h][key], group (key/8) XOR-swizzled by (h&7) — 8 KB

    const int tid  = threadIdx.x;
    const int wave = tid >> 6, lane = tid & 63;
    const int l31  = lane & 31, lhi = lane >> 5;
    const int idx  = blockIdx.x;
    const int b = idx & 7, s = (idx >> 3) % ks, qt = idx / (8 * ks);
    const int slab = T_SEQ / ks, nkt = slab / 64;
    const int qrow0 = qt * 256 + wave * 64;

    const short* qb = qm + ((long)b * T_SEQ + qrow0) * HS;
    const short* kb = km + ((long)b * T_SEQ + s * slab) * HS;
    const short* vb = vtm + (long)b * HS * T_SEQ + s * slab;

    bf16x8 qf[2][4];                       // B-frags: [n=qrow][k=h]
    #pragma unroll
    for (int q = 0; q < 2; ++q)
        #pragma unroll
        for (int kc = 0; kc < 4; ++kc)
            qf[q][kc] = *(const bf16x8*)&qb[(q * 32 + l31) * HS + kc * 16 + lhi * 8];

    f32x16 oacc[2][2] = {};                // [ht][qsub], O^T[h][qrow]
    float lsum[2] = {0.f, 0.f};

    // staging: thread -> row (tid>>2), two 8-short groups g0,g0+1; swizzled LDS offsets
    const int strow = tid >> 2, stc = (tid & 3) * 16, g0 = (tid & 3) * 2;
    const int sw0 = strow * 64 + ((g0 ^ (strow & 7)) * 8);
    const int sw1 = strow * 64 + (((g0 + 1) ^ (strow & 7)) * 8);

    for (int kt = 0; kt < nkt; ++kt) {
        const int k0 = kt * 64;
        bf16x8 ka = *(const bf16x8*)&kb[(k0 + strow) * HS + stc];
        bf16x8 kc2_ = *(const bf16x8*)&kb[(k0 + strow) * HS + stc + 8];
        bf16x8 va = *(const bf16x8*)&vb[strow * T_SEQ + k0 + stc];
        bf16x8 vc2_ = *(const bf16x8*)&vb[strow * T_SEQ + k0 + stc + 8];
        *(bf16x8*)&Kt[sw0] = ka;  *(bf16x8*)&Kt[sw1] = kc2_;
        *(bf16x8*)&Vt[sw0] = va;  *(bf16x8*)&Vt[sw1] = vc2_;
        __syncthreads();

        #pragma unroll
        for (int m = 0; m < 2; ++m) {
            bf16x8 kf[4];                  // A-frags: row=key (m*32+l31)
            #pragma unroll
            for (int kc = 0; kc < 4; ++kc) {
                const int r = m * 32 + l31, gk = kc * 2 + lhi;
                kf[kc] = *(const bf16x8*)&Kt[r * 64 + ((gk ^ (r & 7)) * 8)];
            }
            bf16x8 vf[2][2];               // A-frags: row=h, keys m*32 + kc2*16 + lhi*8
            #pragma unroll
            for (int ht = 0; ht < 2; ++ht)
                #pragma unroll
                for (int j = 0; j < 2; ++j) {
                    const int hr = ht * 32 + l31, gv = (m * 2 + j) * 2 + lhi;
                    vf[ht][j] = *(const bf16x8*)&Vt[hr * 64 + ((gv ^ (hr & 7)) * 8)];
                }

            #pragma unroll
            for (int q = 0; q < 2; ++q) {
                // S^T = K Q^T; C/D: col=qrow=l31, key = 8*quad + 4*lhi + t (+32m)
                f32x16 z = {};
                #pragma unroll
                for (int kc = 0; kc < 4; ++kc)
                    z = __builtin_amdgcn_mfma_f32_32x32x16_bf16(kf[kc], qf[q][kc], z, 0, 0, 0);

                // exp2 -> bf16 (truncated); l sums the SAME truncated values
                uint32_t w[8];
                #pragma unroll
                for (int qd = 0; qd < 4; ++qd) {
                    uint32_t u0 = __builtin_bit_cast(uint32_t, __builtin_amdgcn_exp2f(z[qd * 4 + 0])) & 0xFFFF0000u;
                    uint32_t u1 = __builtin_bit_cast(uint32_t, __builtin_amdgcn_exp2f(z[qd * 4 + 1])) & 0xFFFF0000u;
                    uint32_t u2 = __builtin_bit_cast(uint32_t, __builtin_amdgcn_exp2f(z[qd * 4 + 2])) & 0xFFFF0000u;
                    uint32_t u3 = __builtin_bit_cast(uint32_t, __builtin_amdgcn_exp2f(z[qd * 4 + 3])) & 0xFFFF0000u;
                    lsum[q] += (__builtin_bit_cast(float, u0) + __builtin_bit_cast(float, u1))
                             + (__builtin_bit_cast(float, u2) + __builtin_bit_cast(float, u3));
                    w[qd * 2 + 0] = (u0 >> 16) | u1;   // shorts [key+0, key+1]
                    w[qd * 2 + 1] = (u2 >> 16) | u3;   // shorts [key+2, key+3]
                }
                // lane-pair exchange (lhi 0<->1): assemble PV B-frags
                const bool hi = (lhi != 0);
                uint32_t sa0 = hi ? w[0] : w[2], sa1 = hi ? w[1] : w[3];
                uint32_t sb0 = hi ? w[4] : w[6], sb1 = hi ? w[5] : w[7];
                uint32_t ra0 = (uint32_t)__shfl_xor((int)sa0, 32, 64);
                uint32_t ra1 = (uint32_t)__shfl_xor((int)sa1, 32, 64);
                uint32_t rb0 = (uint32_t)__shfl_xor((int)sb0, 32, 64);
                uint32_t rb1 = (uint32_t)__shfl_xor((int)sb1, 32, 64);
                uint32_t pf0[4], pf1[4];
                pf0[0] = hi ? ra0 : w[0];  pf0[1] = hi ? ra1 : w[1];
                pf0[2] = hi ? w[2] : ra0;  pf0[3] = hi ? w[3] : ra1;
                pf1[0] = hi ? rb0 : w[4];  pf1[1] = hi ? rb1 : w[5];
                pf1[2] = hi ? w[6] : rb0;  pf1[3] = hi ? w[7] : rb1;
                bf16x8 p0 = *(const bf16x8*)pf0, p1 = *(const bf16x8*)pf1;

                #pragma unroll
                for (int ht = 0; ht < 2; ++ht) {
                    oacc[ht][q] = __builtin_amdgcn_mfma_f32_32x32x16_bf16(vf[ht][0], p0, oacc[ht][q], 0, 0, 0);
                    oacc[ht][q] = __builtin_amdgcn_mfma_f32_32x32x16_bf16(vf[ht][1], p1, oacc[ht][q], 0, 0, 0);
                }
            }
        }
        __syncthreads();
    }

    lsum[0] += __shfl_xor(lsum[0], 32, 64);    // lhi halves hold complementary keys
    lsum[1] += __shfl_xor(lsum[1], 32, 64);

    const long rowg = (long)b * T_SEQ + qrow0;
    if (outdirect) {
        float* ob = outdirect + rowg * HS;
        #pragma unroll
        for (int q = 0; q < 2; ++q) {
            const float inv = 1.0f / lsum[q];
            #pragma unroll
            for (int ht = 0; ht < 2; ++ht)
                #pragma unroll
                for (int rq = 0; rq < 4; ++rq) {
                    float4 o;
                    o.x = oacc[ht][q][rq * 4 + 0] * inv; o.y = oacc[ht][q][rq * 4 + 1] * inv;
                    o.z = oacc[ht][q][rq * 4 + 2] * inv; o.w = oacc[ht][q][rq * 4 + 3] * inv;
                    *(float4*)&ob[(long)(q * 32 + l31) * HS + rq * 8 + 4 * lhi + 32 * ht] = o;
                }
        }
    } else {
        float* op = Op + ((long)s * 32768 + rowg) * HS;
        #pragma unroll
        for (int q = 0; q < 2; ++q) {
            #pragma unroll
            for (int ht = 0; ht < 2; ++ht)
                #pragma unroll
                for (int rq = 0; rq < 4; ++rq) {
                    float4 o;
                    o.x = oacc[ht][q][rq * 4 + 0]; o.y = oacc[ht][q][rq * 4 + 1];
                    o.z = oacc[ht][q][rq * 4 + 2]; o.w = oacc[ht][q][rq * 4 + 3];
                    *(float4*)&op[(long)(q * 32 + l31) * HS + rq * 8 + 4 * lhi + 32 * ht] = o;
                }
            if (lhi == 0)
                lp[(long)s * 32768 + rowg + q * 32 + l31] = lsum[q];
        }
    }
}

// ---------------- combine partials: out = sum_s O_s / sum_s l_s ----------------
__global__ __launch_bounds__(256) void combine(const float4* __restrict__ Op,
        const float* __restrict__ lp, float4* __restrict__ out, const int ks) {
    const int idx = blockIdx.x * 256 + threadIdx.x;   // 524288 = 32768 rows x 16 float4
    const int row = idx >> 4, h4 = idx & 15;
    float ox = 0.f, oy = 0.f, oz = 0.f, ow = 0.f, l = 0.f;
    for (int s = 0; s < ks; ++s) {
        float4 t = Op[(long)(s * 32768 + row) * 16 + h4];
        ox += t.x; oy += t.y; oz += t.z; ow += t.w;
        l += lp[s * 32768 + row];
    }
    const float inv = 1.0f / l;
    float4 o; o.x = ox * inv; o.y = oy * inv; o.z = oz * inv; o.w = ow * inv;
    out[(long)row * 16 + h4] = o;
}

extern "C" void kernel_launch(void* const* d_in, const int* in_sizes, int n_in,
                              void* d_out, int out_size, void* d_ws, size_t ws_size,
                              hipStream_t stream) {
    const float* x  = (const float*)d_in[0];
    const float* Wq = (const float*)d_in[1];
    const float* bq = (const float*)d_in[2];
    const float* Wk = (const float*)d_in[3];
    const float* bk = (const float*)d_in[4];
    const float* Wv = (const float*)d_in[5];
    const float* bv = (const float*)d_in[6];

    char* ws = (char*)d_ws;
    short* qo  = (short*)(ws);                     // 4 MB
    short* ko  = (short*)(ws + (4u << 20));        // 4 MB
    short* vto = (short*)(ws + (8u << 20));        // 4 MB  [b][h][t]
    short* wtf = (short*)(ws + (12u << 20));       // 288 KB
    const size_t opOff = 12582912u + 294912u;
    float* Op = (float*)(ws + opOff);

    const size_t per_s = 8388608u + 131072u;       // O partial + l partial per split
    int ks = (ws_size >= opOff + 8 * per_s) ? 8
           : (ws_size >= opOff + 4 * per_s) ? 4
           : (ws_size >= opOff + 2 * per_s) ? 2 : 1;
    float* lp = (float*)(ws + opOff + (size_t)ks * 8388608u);

    prep_wt<<<288, 256, 0, stream>>>(Wq, Wk, Wv, wtf);
    qkv_proj<<<512, 256, 0, stream>>>(x, bq, bk, bv, wtf, qo, ko, vto);
    attn<<<8 * ks * 16, 256, 0, stream>>>(qo, ko, vto, Op, lp, ks,
                                          ks == 1 ? (float*)d_out : nullptr);
    if (ks > 1)
        combine<<<2048, 256, 0, stream>>>((const float4*)Op, lp, (float4*)d_out, ks);
}